// Round 10
// baseline (632.268 us; speedup 1.0000x reference)
//
#include <hip/hip_runtime.h>
#include <cstdint>

// Problem geometry (fixed by the reference)
#define D_IN   4096
#define D_OUT  4096
#define MTOT   16384      // B*S = 8*2048
#define SCALING 2.0f

// GEMM tiling: 256x256 tile, BK=64, 8 waves (2M x 4N), 4-phase, 32x32x16 MFMA
#define BM 256
#define BN 256
#define BK 64
#define KT (D_IN / BK)    // 64 K-tiles

typedef float  f32x16 __attribute__((ext_vector_type(16)));
typedef __bf16 bf16x8 __attribute__((ext_vector_type(8)));
typedef unsigned short ushort8 __attribute__((ext_vector_type(8)));
typedef int    int4v  __attribute__((ext_vector_type(4)));
typedef float  float4v __attribute__((ext_vector_type(4)));

// round-to-nearest-even f32 -> bf16
__device__ __forceinline__ unsigned short f2bf(float f) {
  union { float f; unsigned u; } v; v.f = f;
  unsigned r = v.u + 0x7FFF + ((v.u >> 16) & 1);
  return (unsigned short)(r >> 16);
}

// async global->LDS, 16B per lane (wave-uniform base + lane*16 on LDS side)
#define ASYNC16(g, l)                                                        \
  __builtin_amdgcn_global_load_lds(                                          \
      (const __attribute__((address_space(1))) unsigned int*)(g),            \
      (__attribute__((address_space(3))) unsigned int*)(l), 16, 0, 0)

#define BAR    __builtin_amdgcn_s_barrier()
#define VMW(n) asm volatile("s_waitcnt vmcnt(" #n ")" ::: "memory")

// ---------------------------------------------------------------- prep: x -> bf16
__global__ __launch_bounds__(256) void prep_x_kernel(const float* __restrict__ x,
                                                     unsigned short* __restrict__ xbf) {
  int i = (blockIdx.x * 256 + threadIdx.x) * 8;
  float4v lo = *(const float4v*)(x + i);
  float4v hi = *(const float4v*)(x + i + 4);
  ushort8 o;
  o[0] = f2bf(lo[0]); o[1] = f2bf(lo[1]); o[2] = f2bf(lo[2]); o[3] = f2bf(lo[3]);
  o[4] = f2bf(hi[0]); o[5] = f2bf(hi[1]); o[6] = f2bf(hi[2]); o[7] = f2bf(hi[3]);
  *(ushort8*)(xbf + i) = o;
}

// ------------------------------------------- prep: W_eff = dequant(codes)+2*delta
__global__ __launch_bounds__(256) void prep_w_kernel(const int* __restrict__ codes,
                                                     const float* __restrict__ scales,
                                                     const float* __restrict__ delta,
                                                     unsigned short* __restrict__ weff) {
  int i = (blockIdx.x * 256 + threadIdx.x) * 8;   // 8 consecutive elems, same group
  int row = i >> 12;          // / D_IN
  int col = i & (D_IN - 1);
  float s = scales[(row << 6) + (col >> 6)];      // 64 groups per row
  int4v   c0 = *(const int4v*)(codes + i);
  int4v   c1 = *(const int4v*)(codes + i + 4);
  float4v d0 = *(const float4v*)(delta + i);
  float4v d1 = *(const float4v*)(delta + i + 4);
  ushort8 o;
  o[0] = f2bf((float)(c0[0] - 8) * s + SCALING * d0[0]);
  o[1] = f2bf((float)(c0[1] - 8) * s + SCALING * d0[1]);
  o[2] = f2bf((float)(c0[2] - 8) * s + SCALING * d0[2]);
  o[3] = f2bf((float)(c0[3] - 8) * s + SCALING * d0[3]);
  o[4] = f2bf((float)(c1[0] - 8) * s + SCALING * d1[0]);
  o[5] = f2bf((float)(c1[1] - 8) * s + SCALING * d1[1]);
  o[6] = f2bf((float)(c1[2] - 8) * s + SCALING * d1[2]);
  o[7] = f2bf((float)(c1[3] - 8) * s + SCALING * d1[3]);
  *(ushort8*)(weff + i) = o;
}

// ---------------------------------------------------------------- main GEMM
// C[M][N] = Xbf[M][K] * Weff[N][K]^T + bias
// Round-9 skeleton (proven staging/drain), MFMA swapped to 32x32x16:
// per wave: 4 m-subtiles x 2 n-subtiles of 32x32 (acc = 8 x f32x16 = 128 VGPR),
// K-tile 64 = 4 k-steps of 16. Phases (one (mh,nh) quadrant, 8 MFMA each):
//   Ph0: rd A(mh0) 8 + B0 4 | stage A(g+1)h0 | BAR | MM8(A0,B0) | BAR
//   Ph1: rd B1 4            | stage A(g+1)h1 | BAR | MM8(A0,B1) | BAR
//   Ph2: rd A(mh1) 8        | stage B(g+2)h0 | BAR | MM8(A1,B0) | BAR
//   Ph3:                    | stage B(g+2)h1 | vmcnt(4) | BAR | MM8(A1,B1) | BAR
// Ph3 vmcnt(4): queue = B(g+1)x4, A(g+1)x4, B(g+2)x4 -> drains tile g+1
// completely (all 4 slots are read at next Ph0 by some wave), leaves B(g+2)
// in flight. 32x32x16 operand layout: lane l = row/col l&31, k-elems
// (l>>5)*8 + j (gfx950 2xK doubling of the CDNA3 32x32x8 map); under the
// st-swizzle the lane's k-chunk is (2k + (l>>5)) ^ (l&7). C/D layout
// [m74/m101-verified]: col = lane&31, row = (reg&3) + 8*(reg>>2) + 4*(lane>>5).
// LDS slots/buf: [A0 rows0-127][A1][B0][B1], each [128][64] bf16, XOR-swizzled
// byte ^= ((row&7)<<4): inverse-swizzled global source + swizzled ds_read.
// Loop unrolled x2 so buf is a LITERAL (immediate-offset folding).

#define STAGE_A(buf_, kt_, h_) do {                                          \
    char* d_ = &lds[buf_][h_][0] + tid * 16;                                 \
    const unsigned short* s_ = gA + (size_t)(h_) * 128 * D_IN + (kt_) * 64;  \
    ASYNC16(s_, d_);                                                         \
    ASYNC16(s_ + 64 * D_IN, d_ + 8192);                                      \
  } while (0)

#define STAGE_B(buf_, kt_, h_) do {                                          \
    char* d_ = &lds[buf_][2 + (h_)][0] + tid * 16;                           \
    const unsigned short* s_ = gB + (size_t)(h_) * 128 * D_IN + (kt_) * 64;  \
    ASYNC16(s_, d_);                                                         \
    ASYNC16(s_ + 64 * D_IN, d_ + 8192);                                      \
  } while (0)

// read A m-half mh_ (2 x 32-row subtiles, 4 k-steps each) -> Af[2][4]
#define RD_A32(buf_, mh_) do {                                               \
    _Pragma("unroll")                                                        \
    for (int m2 = 0; m2 < 2; ++m2) {                                         \
      const char* p_ = &lds[buf_][wr][0] + ((mh_)*2 + m2) * 4096 + rowb32;   \
      _Pragma("unroll")                                                      \
      for (int k = 0; k < 4; ++k)                                            \
        Af[m2][k] = *(const bf16x8*)(p_ + koffk[k]);                         \
    } } while (0)

// read B n-subtile nh_ (32 cols, 4 k-steps) -> dst_[4]
#define RD_B32(buf_, nh_, dst_) do {                                         \
    const char* p_ = &lds[buf_][2 + (wc >> 1)][0] + (wc & 1) * 8192 +        \
                     (nh_) * 4096 + rowb32;                                  \
    _Pragma("unroll")                                                        \
    for (int k = 0; k < 4; ++k)                                              \
      dst_[k] = *(const bf16x8*)(p_ + koffk[k]);                             \
  } while (0)

// 8 MFMA (32x32x16): quadrant (mh_, nh_), k-outer for 2 independent acc chains
#define MM8(bfr_, mh_, nh_) do {                                             \
    __builtin_amdgcn_s_setprio(1);                                           \
    _Pragma("unroll")                                                        \
    for (int k = 0; k < 4; ++k) {                                            \
      _Pragma("unroll")                                                      \
      for (int m2 = 0; m2 < 2; ++m2) {                                       \
        acc[(mh_)*2 + m2][nh_] = __builtin_amdgcn_mfma_f32_32x32x16_bf16(    \
            Af[m2][k], bfr_[k], acc[(mh_)*2 + m2][nh_], 0, 0, 0);            \
      } }                                                                    \
    __builtin_amdgcn_s_setprio(0);                                           \
  } while (0)

// One K-tile. buf_ MUST be literal 0/1. SA_/SB_ compile-time guards;
// VM_ is the vmcnt statement at Ph3 (before its pre-MFMA barrier).
#define KTILE(buf_, g_, SA_, SB_, VM_) do {                                  \
    /* Ph0 */                                                                \
    RD_A32(buf_, 0);                                                         \
    RD_B32(buf_, 0, B0f);                                                    \
    if (SA_) STAGE_A((buf_) ^ 1, (g_) + 1, 0);                               \
    BAR;                                                                     \
    MM8(B0f, 0, 0);                                                          \
    BAR;                                                                     \
    /* Ph1 */                                                                \
    RD_B32(buf_, 1, B1f);                                                    \
    if (SA_) STAGE_A((buf_) ^ 1, (g_) + 1, 1);                               \
    BAR;                                                                     \
    MM8(B1f, 0, 1);                                                          \
    BAR;                                                                     \
    /* Ph2 */                                                                \
    RD_A32(buf_, 1);                                                         \
    if (SB_) STAGE_B(buf_, (g_) + 2, 0);                                     \
    BAR;                                                                     \
    MM8(B0f, 1, 0);                                                          \
    BAR;                                                                     \
    /* Ph3: whole-tile(g+1) drain before the barrier next Ph0 reads behind */ \
    if (SB_) STAGE_B(buf_, (g_) + 2, 1);                                     \
    VM_;                                                                     \
    BAR;                                                                     \
    MM8(B1f, 1, 1);                                                          \
    BAR;                                                                     \
  } while (0)

__global__ __launch_bounds__(512, 2) void gemm8_kernel(const unsigned short* __restrict__ xbf,
                                                       const unsigned short* __restrict__ weff,
                                                       const float* __restrict__ bias,
                                                       float* __restrict__ out) {
  __shared__ __attribute__((aligned(1024))) char lds[2][4][16384];  // 128 KiB

  const int tid  = threadIdx.x;
  const int lane = tid & 63;
  const int wid  = tid >> 6;
  const int wr   = wid >> 2;        // 0..1  (M half)
  const int wc   = wid & 3;         // 0..3  (N quarter)

  // bijective XCD swizzle: 1024 wgs, 8 XCDs -> each XCD gets 8 M-rows x 16 N-cols
  const int id  = blockIdx.x;
  const int nid = (id & 7) * 128 + (id >> 3);
  const int tn  = nid & 15;         // N tile (16)
  const int tm  = nid >> 4;         // M tile (64)

  // 32x32 operand lane offsets (swizzled):
  //   row = lane&31 ; k-step k reads global k-chunk 2k+(lane>>5),
  //   stored at LDS chunk (2k+(lane>>5)) ^ (lane&7) within the row.
  const int rowb32 = (lane & 31) * 128;
  const int l5 = lane >> 5;
  const int lx = lane & 7;
  int koffk[4];
#pragma unroll
  for (int k = 0; k < 4; ++k) koffk[k] = ((2 * k + l5) ^ lx) << 4;

  // staging lane offsets (inverse-swizzled source)
  const int sr = tid >> 3;                        // row within 64-row chunk
  const int ke = ((tid & 7) ^ (sr & 7)) * 8;      // permuted k-element offset
  const unsigned short* gA = xbf  + (size_t)(tm * BM + sr) * D_IN + ke;
  const unsigned short* gB = weff + (size_t)(tn * BN + sr) * D_IN + ke;

  f32x16 acc[4][2] = {};
  bf16x8 Af[2][4], B0f[4], B1f[4];

  // prologue: tile 0 (A+B) -> buf0 ; B of tile 1 -> buf1  (12 loads)
  STAGE_A(0, 0, 0); STAGE_A(0, 0, 1);
  STAGE_B(0, 0, 0); STAGE_B(0, 0, 1);
  STAGE_B(1, 1, 0); STAGE_B(1, 1, 1);
  VMW(4);           // tile 0 fully landed; B(1)x4 stays in flight
  BAR;

  for (int g = 0; g < KT - 2; g += 2) {
    KTILE(0, g,     1, 1, VMW(4));
    KTILE(1, g + 1, 1, 1, VMW(4));
  }
  // tile KT-2 (buf0): stages A(KT-1) only; Ph3 queue = B(KT-1)x4 + A(KT-1)x4
  //   -> full drain so tile KT-1 is complete before its Ph0.
  KTILE(0, KT - 2, 1, 0, VMW(0));
  // tile KT-1 (buf1): pure compute
  KTILE(1, KT - 1, 0, 0, (void)0);

  // epilogue: C/D layout col = lane&31, row = (reg&3)+8*(reg>>2)+4*(lane>>5)
  const int row0 = tm * BM + wr * 128 + 4 * l5;
  const int col0 = tn * BN + wc * 64 + (lane & 31);
#pragma unroll
  for (int ns = 0; ns < 2; ++ns) {
    const int col = col0 + ns * 32;
    const float bv = bias[col];
#pragma unroll
    for (int ms = 0; ms < 4; ++ms) {
      const int rbase = row0 + ms * 32;
#pragma unroll
      for (int j = 0; j < 16; ++j) {
        const int r = rbase + (j & 3) + 8 * (j >> 2);
        out[(size_t)r * D_OUT + col] = acc[ms][ns][j] + bv;
      }
    }
  }
}

extern "C" void kernel_launch(void* const* d_in, const int* in_sizes, int n_in,
                              void* d_out, int out_size, void* d_ws, size_t ws_size,
                              hipStream_t stream) {
  const float* x      = (const float*)d_in[0];
  const int*   codes  = (const int*)d_in[1];
  const float* scales = (const float*)d_in[2];
  const float* bias   = (const float*)d_in[3];
  const float* delta  = (const float*)d_in[4];
  float* out = (float*)d_out;

  unsigned short* xbf  = (unsigned short*)d_ws;                    // 128 MiB
  unsigned short* weff = xbf + (size_t)MTOT * D_IN;                // +32 MiB

  prep_x_kernel<<<(MTOT * D_IN) / (256 * 8), 256, 0, stream>>>(x, xbf);
  prep_w_kernel<<<(D_OUT * D_IN) / (256 * 8), 256, 0, stream>>>(codes, scales, delta, weff);

  gemm8_kernel<<<(MTOT / BM) * (D_OUT / BN), 512, 0, stream>>>(xbf, weff, bias, out);
}

// Round 11
// 572.086 us; speedup vs baseline: 1.1052x; 1.1052x over previous
//
#include <hip/hip_runtime.h>
#include <cstdint>

// Problem geometry (fixed by the reference)
#define D_IN   4096
#define D_OUT  4096
#define MTOT   16384      // B*S = 8*2048
#define SCALING 2.0f

// GEMM tiling: 256x256 tile, BK=64, 8 waves (2M x 4N), 4-phase, reads POST-barrier
#define BM 256
#define BN 256
#define BK 64
#define KT (D_IN / BK)    // 64 K-tiles

typedef float  f32x4  __attribute__((ext_vector_type(4)));
typedef __bf16 bf16x8 __attribute__((ext_vector_type(8)));
typedef unsigned short ushort8 __attribute__((ext_vector_type(8)));
typedef int    int4v  __attribute__((ext_vector_type(4)));
typedef float  float4v __attribute__((ext_vector_type(4)));

// round-to-nearest-even f32 -> bf16
__device__ __forceinline__ unsigned short f2bf(float f) {
  union { float f; unsigned u; } v; v.f = f;
  unsigned r = v.u + 0x7FFF + ((v.u >> 16) & 1);
  return (unsigned short)(r >> 16);
}

// async global->LDS, 16B per lane (wave-uniform base + lane*16 on LDS side)
#define ASYNC16(g, l)                                                        \
  __builtin_amdgcn_global_load_lds(                                          \
      (const __attribute__((address_space(1))) unsigned int*)(g),            \
      (__attribute__((address_space(3))) unsigned int*)(l), 16, 0, 0)

#define BAR    __builtin_amdgcn_s_barrier()
#define VMW(n) asm volatile("s_waitcnt vmcnt(" #n ")" ::: "memory")

// ---------------------------------------------------------------- prep: x -> bf16
__global__ __launch_bounds__(256) void prep_x_kernel(const float* __restrict__ x,
                                                     unsigned short* __restrict__ xbf) {
  int i = (blockIdx.x * 256 + threadIdx.x) * 8;
  float4v lo = *(const float4v*)(x + i);
  float4v hi = *(const float4v*)(x + i + 4);
  ushort8 o;
  o[0] = f2bf(lo[0]); o[1] = f2bf(lo[1]); o[2] = f2bf(lo[2]); o[3] = f2bf(lo[3]);
  o[4] = f2bf(hi[0]); o[5] = f2bf(hi[1]); o[6] = f2bf(hi[2]); o[7] = f2bf(hi[3]);
  *(ushort8*)(xbf + i) = o;
}

// ------------------------------------------- prep: W_eff = dequant(codes)+2*delta
__global__ __launch_bounds__(256) void prep_w_kernel(const int* __restrict__ codes,
                                                     const float* __restrict__ scales,
                                                     const float* __restrict__ delta,
                                                     unsigned short* __restrict__ weff) {
  int i = (blockIdx.x * 256 + threadIdx.x) * 8;   // 8 consecutive elems, same group
  int row = i >> 12;          // / D_IN
  int col = i & (D_IN - 1);
  float s = scales[(row << 6) + (col >> 6)];      // 64 groups per row
  int4v   c0 = *(const int4v*)(codes + i);
  int4v   c1 = *(const int4v*)(codes + i + 4);
  float4v d0 = *(const float4v*)(delta + i);
  float4v d1 = *(const float4v*)(delta + i + 4);
  ushort8 o;
  o[0] = f2bf((float)(c0[0] - 8) * s + SCALING * d0[0]);
  o[1] = f2bf((float)(c0[1] - 8) * s + SCALING * d0[1]);
  o[2] = f2bf((float)(c0[2] - 8) * s + SCALING * d0[2]);
  o[3] = f2bf((float)(c0[3] - 8) * s + SCALING * d0[3]);
  o[4] = f2bf((float)(c1[0] - 8) * s + SCALING * d1[0]);
  o[5] = f2bf((float)(c1[1] - 8) * s + SCALING * d1[1]);
  o[6] = f2bf((float)(c1[2] - 8) * s + SCALING * d1[2]);
  o[7] = f2bf((float)(c1[3] - 8) * s + SCALING * d1[3]);
  *(ushort8*)(weff + i) = o;
}

// ---------------------------------------------------------------- main GEMM
// C[M][N] = Xbf[M][K] * Weff[N][K]^T + bias
// 256x256, BK=64, 512 thr (8 waves: wr=wid>>2, wc=wid&3), 4 phases/K-tile,
// one C-quadrant x K=64 (16 MFMA) per phase. ds_reads issued AFTER the
// pre-MFMA barrier (not before): first MFMA starts when its own frags land
// (compiler-counted lgkm); read-burst tail drains under this phase's MFMAs;
// previous phase's MFMA chain (different acc quadrant, independent) is still
// in the matrix pipe across the barrier (s_barrier syncs instruction streams,
// not MFMA results) -> LDS and MFMA pipes overlap instead of serializing.
//   Ph0: stage A(g+1)h0 | BAR | rd A0(8)+B0(4), MM16(A0,B0) | BAR
//   Ph1: stage A(g+1)h1 | BAR | rd B1(4),       MM16(A0,B1) | BAR
//   Ph2: stage B(g+2)h0 | BAR | rd A1(8),       MM16(A1,B0) | BAR
//   Ph3: stage B(g+2)h1 | vmcnt(4) | BAR |      MM16(A1,B1) | BAR
// Cross-wave drain (round-8 lesson): slot select is per-WAVE (A: wr,
// B: 2+(wc>>1)) so ALL slots of a tile are read at Ph0 -> whole-tile drain:
// Ph3's vmcnt(4) (queue B(g+1)x4,A(g+1)x4,B(g+2)x4 = 12) drains tile g+1
// fully one barrier before its Ph0 reads, leaves B(g+2) in flight (never 0).
// Per-wave read-WAR vs staging writes closed: last MFMA's lgkm wait drains
// all that wave's reads before it crosses the post-MM barrier.
// LDS slots/buf: [A0 rows0-127][A1][B0][B1], each [128][64] bf16, XOR-swizzled
// byte ^= ((row&7)<<4): inverse-swizzled global source + swizzled ds_read.
// Loop unrolled x2 so buf is a LITERAL (immediate-offset folding).

#define STAGE_A(buf_, kt_, h_) do {                                          \
    char* d_ = &lds[buf_][h_][0] + tid * 16;                                 \
    const unsigned short* s_ = gA + (size_t)(h_) * 128 * D_IN + (kt_) * 64;  \
    ASYNC16(s_, d_);                                                         \
    ASYNC16(s_ + 64 * D_IN, d_ + 8192);                                      \
  } while (0)

#define STAGE_B(buf_, kt_, h_) do {                                          \
    char* d_ = &lds[buf_][2 + (h_)][0] + tid * 16;                           \
    const unsigned short* s_ = gB + (size_t)(h_) * 128 * D_IN + (kt_) * 64;  \
    ASYNC16(s_, d_);                                                         \
    ASYNC16(s_ + 64 * D_IN, d_ + 8192);                                      \
  } while (0)

// read A-half h_ (4 m-frags, rows h*64..h*64+63 of wave's panel) -> A[4][2]
#define RD_A(buf_, h_) do {                                                  \
    _Pragma("unroll")                                                        \
    for (int m2 = 0; m2 < 4; ++m2) {                                         \
      const char* p_ = &lds[buf_][wr][0] + ((h_)*4 + m2) * 2048 + rowb;      \
      A[m2][0] = *(const bf16x8*)(p_ + koff0);                               \
      A[m2][1] = *(const bf16x8*)(p_ + koff1);                               \
    } } while (0)

// read B-half h_ (2 n-frags) of the wave's 64-col B panel
#define RD_B(buf_, h_, dst_) do {                                            \
    _Pragma("unroll")                                                        \
    for (int n2 = 0; n2 < 2; ++n2) {                                         \
      const char* p_ = &lds[buf_][2 + (wc >> 1)][0] + (wc & 1) * 8192 +      \
                       (h_) * 4096 + n2 * 2048 + rowb;                       \
      dst_[n2][0] = *(const bf16x8*)(p_ + koff0);                            \
      dst_[n2][1] = *(const bf16x8*)(p_ + koff1);                            \
    } } while (0)

// 16 MFMA: A-half (acc rows mh*4..+3) x B-half (acc cols nh*2..+1), K=64
#define MM16(bfr_, mh_, nh_) do {                                            \
    __builtin_amdgcn_s_setprio(1);                                           \
    _Pragma("unroll")                                                        \
    for (int m2 = 0; m2 < 4; ++m2) {                                         \
      _Pragma("unroll")                                                      \
      for (int n2 = 0; n2 < 2; ++n2) {                                       \
        acc[(mh_)*4 + m2][(nh_)*2 + n2] = __builtin_amdgcn_mfma_f32_16x16x32_bf16( \
            A[m2][0], bfr_[n2][0], acc[(mh_)*4 + m2][(nh_)*2 + n2], 0, 0, 0);      \
        acc[(mh_)*4 + m2][(nh_)*2 + n2] = __builtin_amdgcn_mfma_f32_16x16x32_bf16( \
            A[m2][1], bfr_[n2][1], acc[(mh_)*4 + m2][(nh_)*2 + n2], 0, 0, 0);      \
      } }                                                                    \
    __builtin_amdgcn_s_setprio(0);                                           \
  } while (0)

// One K-tile. buf_ MUST be literal 0/1. SA_/SB_ compile-time guards;
// VM_ is the vmcnt statement at Ph3 (before its pre-MFMA barrier).
#define KTILE(buf_, g_, SA_, SB_, VM_) do {                                  \
    /* Ph0 */                                                                \
    if (SA_) STAGE_A((buf_) ^ 1, (g_) + 1, 0);                               \
    BAR;                                                                     \
    RD_A(buf_, 0);                                                           \
    RD_B(buf_, 0, B0);                                                       \
    MM16(B0, 0, 0);                                                          \
    BAR;                                                                     \
    /* Ph1 */                                                                \
    if (SA_) STAGE_A((buf_) ^ 1, (g_) + 1, 1);                               \
    BAR;                                                                     \
    RD_B(buf_, 1, B1);                                                       \
    MM16(B1, 0, 1);                                                          \
    BAR;                                                                     \
    /* Ph2 */                                                                \
    if (SB_) STAGE_B(buf_, (g_) + 2, 0);                                     \
    BAR;                                                                     \
    RD_A(buf_, 1);                                                           \
    MM16(B0, 1, 0);                                                          \
    BAR;                                                                     \
    /* Ph3: whole-tile(g+1) drain before the barrier next Ph0 reads behind */ \
    if (SB_) STAGE_B(buf_, (g_) + 2, 1);                                     \
    VM_;                                                                     \
    BAR;                                                                     \
    MM16(B1, 1, 1);                                                          \
    BAR;                                                                     \
  } while (0)

__global__ __launch_bounds__(512, 2) void gemm8_kernel(const unsigned short* __restrict__ xbf,
                                                       const unsigned short* __restrict__ weff,
                                                       const float* __restrict__ bias,
                                                       float* __restrict__ out) {
  __shared__ __attribute__((aligned(1024))) char lds[2][4][16384];  // 128 KiB

  const int tid  = threadIdx.x;
  const int lane = tid & 63;
  const int wid  = tid >> 6;
  const int wr   = wid >> 2;        // 0..1  (M half)
  const int wc   = wid & 3;         // 0..3  (N quarter)

  // bijective XCD swizzle: 1024 wgs, 8 XCDs -> each XCD gets 8 M-rows x 16 N-cols
  const int id  = blockIdx.x;
  const int nid = (id & 7) * 128 + (id >> 3);
  const int tn  = nid & 15;         // N tile (16)
  const int tm  = nid >> 4;         // M tile (64)

  // ds_read lane offsets (swizzled): addr = row*128 + ((kk*64 + (l>>4)*16) ^ ((l&7)<<4))
  const int rowb  = (lane & 15) * 128;
  const int kx    = (lane & 7) << 4;
  const int koff0 = (((lane >> 4) * 16) ^ kx);
  const int koff1 = ((64 + (lane >> 4) * 16) ^ kx);

  // staging lane offsets (inverse-swizzled source)
  const int sr = tid >> 3;                        // row within 64-row chunk
  const int ke = ((tid & 7) ^ (sr & 7)) * 8;      // permuted k-element offset
  const unsigned short* gA = xbf  + (size_t)(tm * BM + sr) * D_IN + ke;
  const unsigned short* gB = weff + (size_t)(tn * BN + sr) * D_IN + ke;

  f32x4 acc[8][4] = {};
  bf16x8 A[4][2], B0[2][2], B1[2][2];

  // prologue: tile 0 (A+B) -> buf0 ; B of tile 1 -> buf1  (12 loads)
  STAGE_A(0, 0, 0); STAGE_A(0, 0, 1);
  STAGE_B(0, 0, 0); STAGE_B(0, 0, 1);
  STAGE_B(1, 1, 0); STAGE_B(1, 1, 1);
  VMW(4);           // tile 0 fully landed; B(1)x4 stays in flight
  BAR;

  for (int g = 0; g < KT - 2; g += 2) {
    KTILE(0, g,     1, 1, VMW(4));
    KTILE(1, g + 1, 1, 1, VMW(4));
  }
  // tile KT-2 (buf0): stages A(KT-1) only; Ph3 queue = B(KT-1)x4 + A(KT-1)x4
  //   -> full drain so tile KT-1 is complete before its Ph0.
  KTILE(0, KT - 2, 1, 0, VMW(0));
  // tile KT-1 (buf1): pure compute
  KTILE(1, KT - 1, 0, 0, (void)0);

  // epilogue: C/D layout col = lane&15, row = (lane>>4)*4 + j  [m89-verified]
  const int row0 = tm * BM + wr * 128 + (lane >> 4) * 4;
  const int col0 = tn * BN + wc * 64 + (lane & 15);
#pragma unroll
  for (int n = 0; n < 4; ++n) {
    const int col = col0 + n * 16;
    const float bv = bias[col];
#pragma unroll
    for (int m = 0; m < 8; ++m) {
      const int r = row0 + m * 16;
#pragma unroll
      for (int j = 0; j < 4; ++j)
        out[(size_t)(r + j) * D_OUT + col] = acc[m][n][j] + bv;
    }
  }
}

extern "C" void kernel_launch(void* const* d_in, const int* in_sizes, int n_in,
                              void* d_out, int out_size, void* d_ws, size_t ws_size,
                              hipStream_t stream) {
  const float* x      = (const float*)d_in[0];
  const int*   codes  = (const int*)d_in[1];
  const float* scales = (const float*)d_in[2];
  const float* bias   = (const float*)d_in[3];
  const float* delta  = (const float*)d_in[4];
  float* out = (float*)d_out;

  unsigned short* xbf  = (unsigned short*)d_ws;                    // 128 MiB
  unsigned short* weff = xbf + (size_t)MTOT * D_IN;                // +32 MiB

  prep_x_kernel<<<(MTOT * D_IN) / (256 * 8), 256, 0, stream>>>(x, xbf);
  prep_w_kernel<<<(D_OUT * D_IN) / (256 * 8), 256, 0, stream>>>(codes, scales, delta, weff);

  gemm8_kernel<<<(MTOT / BM) * (D_OUT / BN), 512, 0, stream>>>(xbf, weff, bias, out);
}

// Round 12
// 556.395 us; speedup vs baseline: 1.1364x; 1.0282x over previous
//
#include <hip/hip_runtime.h>
#include <cstdint>

// Problem geometry (fixed by the reference)
#define D_IN   4096
#define D_OUT  4096
#define MTOT   16384      // B*S = 8*2048
#define SCALING 2.0f

// GEMM tiling: 256x256 tile, BK=64, 8 waves (2M x 4N), 4 single-barrier phases
#define BM 256
#define BN 256
#define BK 64
#define KT (D_IN / BK)    // 64 K-tiles

typedef float  f32x4  __attribute__((ext_vector_type(4)));
typedef __bf16 bf16x8 __attribute__((ext_vector_type(8)));
typedef unsigned short ushort8 __attribute__((ext_vector_type(8)));
typedef int    int4v  __attribute__((ext_vector_type(4)));
typedef float  float4v __attribute__((ext_vector_type(4)));

// round-to-nearest-even f32 -> bf16
__device__ __forceinline__ unsigned short f2bf(float f) {
  union { float f; unsigned u; } v; v.f = f;
  unsigned r = v.u + 0x7FFF + ((v.u >> 16) & 1);
  return (unsigned short)(r >> 16);
}

// async global->LDS, 16B per lane (wave-uniform base + lane*16 on LDS side)
#define ASYNC16(g, l)                                                        \
  __builtin_amdgcn_global_load_lds(                                          \
      (const __attribute__((address_space(1))) unsigned int*)(g),            \
      (__attribute__((address_space(3))) unsigned int*)(l), 16, 0, 0)

#define BAR    __builtin_amdgcn_s_barrier()
#define VMW(n) asm volatile("s_waitcnt vmcnt(" #n ")" ::: "memory")

// ---------------------------------------------------------------- prep: x -> bf16
__global__ __launch_bounds__(256) void prep_x_kernel(const float* __restrict__ x,
                                                     unsigned short* __restrict__ xbf) {
  int i = (blockIdx.x * 256 + threadIdx.x) * 8;
  float4v lo = *(const float4v*)(x + i);
  float4v hi = *(const float4v*)(x + i + 4);
  ushort8 o;
  o[0] = f2bf(lo[0]); o[1] = f2bf(lo[1]); o[2] = f2bf(lo[2]); o[3] = f2bf(lo[3]);
  o[4] = f2bf(hi[0]); o[5] = f2bf(hi[1]); o[6] = f2bf(hi[2]); o[7] = f2bf(hi[3]);
  *(ushort8*)(xbf + i) = o;
}

// ------------------------------------------- prep: W_eff = dequant(codes)+2*delta
__global__ __launch_bounds__(256) void prep_w_kernel(const int* __restrict__ codes,
                                                     const float* __restrict__ scales,
                                                     const float* __restrict__ delta,
                                                     unsigned short* __restrict__ weff) {
  int i = (blockIdx.x * 256 + threadIdx.x) * 8;   // 8 consecutive elems, same group
  int row = i >> 12;          // / D_IN
  int col = i & (D_IN - 1);
  float s = scales[(row << 6) + (col >> 6)];      // 64 groups per row
  int4v   c0 = *(const int4v*)(codes + i);
  int4v   c1 = *(const int4v*)(codes + i + 4);
  float4v d0 = *(const float4v*)(delta + i);
  float4v d1 = *(const float4v*)(delta + i + 4);
  ushort8 o;
  o[0] = f2bf((float)(c0[0] - 8) * s + SCALING * d0[0]);
  o[1] = f2bf((float)(c0[1] - 8) * s + SCALING * d0[1]);
  o[2] = f2bf((float)(c0[2] - 8) * s + SCALING * d0[2]);
  o[3] = f2bf((float)(c0[3] - 8) * s + SCALING * d0[3]);
  o[4] = f2bf((float)(c1[0] - 8) * s + SCALING * d1[0]);
  o[5] = f2bf((float)(c1[1] - 8) * s + SCALING * d1[1]);
  o[6] = f2bf((float)(c1[2] - 8) * s + SCALING * d1[2]);
  o[7] = f2bf((float)(c1[3] - 8) * s + SCALING * d1[3]);
  *(ushort8*)(weff + i) = o;
}

// ---------------------------------------------------------------- main GEMM
// C[M][N] = Xbf[M][K] * Weff[N][K]^T + bias
// 256x256, BK=64, 512 thr (8 waves: wr=wid>>2, wc=wid&3).
// FOUR single-barrier phases per K-tile (8 -> 4 barriers):
//   P0: stage A(g+1)h0 | BAR | rd A0(8)+B0(4), MM16(A0,B0)
//   P1: stage A(g+1)h1 | BAR | rd B1(4),       MM16(A0,B1)
//   P2: stage B(g+2)h0 | BAR | rd A1(8),       MM16(A1,B0)
//   P3: stage B(g+2)h1 | BAR |                 MM16(A1,B1) | vmcnt(4)
// Single-barrier WAR audit (waves are at most ONE phase apart; a STAGE at
// phase-p-top only races phase p-1 readers):
//   P0 stages buf^1.A0 : P3 reads nothing            -> safe
//   P1 stages buf^1.A1 : P0 reads buf slots only     -> safe
//   P2 stages buf.B0   : P1 reads buf.B1 only        -> safe
//   P3 stages buf.B1   : P2 reads buf.A1 only        -> safe
// Each wave's ds_reads are lgkm-drained by its own MM16 before it reaches the
// next barrier, so one barrier separates every slot's last read from its
// overwrite. Whole-tile drain (round-8 lesson: all 4 slots are read at P0 by
// wave-dependent slot selects): vmcnt(4) at tile end, queue = B(g+1)x4,
// A(g+1)x4, B(g+2)x4 = 12 -> drains tile g+1 fully, leaves B(g+2) (never 0).
// LDS slots/buf: [A0 rows0-127][A1][B0][B1], each [128][64] bf16, XOR-swizzled
// byte ^= ((row&7)<<4): inverse-swizzled global source + swizzled ds_read.
// Loop unrolled x2 so buf is a LITERAL (immediate-offset folding).

#define STAGE_A(buf_, kt_, h_) do {                                          \
    char* d_ = &lds[buf_][h_][0] + tid * 16;                                 \
    const unsigned short* s_ = gA + (size_t)(h_) * 128 * D_IN + (kt_) * 64;  \
    ASYNC16(s_, d_);                                                         \
    ASYNC16(s_ + 64 * D_IN, d_ + 8192);                                      \
  } while (0)

#define STAGE_B(buf_, kt_, h_) do {                                          \
    char* d_ = &lds[buf_][2 + (h_)][0] + tid * 16;                           \
    const unsigned short* s_ = gB + (size_t)(h_) * 128 * D_IN + (kt_) * 64;  \
    ASYNC16(s_, d_);                                                         \
    ASYNC16(s_ + 64 * D_IN, d_ + 8192);                                      \
  } while (0)

// read A-half h_ (4 m-frags, rows h*64..h*64+63 of wave's panel) -> A[4][2]
#define RD_A(buf_, h_) do {                                                  \
    _Pragma("unroll")                                                        \
    for (int m2 = 0; m2 < 4; ++m2) {                                         \
      const char* p_ = &lds[buf_][wr][0] + ((h_)*4 + m2) * 2048 + rowb;      \
      A[m2][0] = *(const bf16x8*)(p_ + koff0);                               \
      A[m2][1] = *(const bf16x8*)(p_ + koff1);                               \
    } } while (0)

// read B-half h_ (2 n-frags) of the wave's 64-col B panel
#define RD_B(buf_, h_, dst_) do {                                            \
    _Pragma("unroll")                                                        \
    for (int n2 = 0; n2 < 2; ++n2) {                                         \
      const char* p_ = &lds[buf_][2 + (wc >> 1)][0] + (wc & 1) * 8192 +      \
                       (h_) * 4096 + n2 * 2048 + rowb;                       \
      dst_[n2][0] = *(const bf16x8*)(p_ + koff0);                            \
      dst_[n2][1] = *(const bf16x8*)(p_ + koff1);                            \
    } } while (0)

// 16 MFMA: A-half (acc rows mh*4..+3) x B-half (acc cols nh*2..+1), K=64
#define MM16(bfr_, mh_, nh_) do {                                            \
    __builtin_amdgcn_s_setprio(1);                                           \
    _Pragma("unroll")                                                        \
    for (int m2 = 0; m2 < 4; ++m2) {                                         \
      _Pragma("unroll")                                                      \
      for (int n2 = 0; n2 < 2; ++n2) {                                       \
        acc[(mh_)*4 + m2][(nh_)*2 + n2] = __builtin_amdgcn_mfma_f32_16x16x32_bf16( \
            A[m2][0], bfr_[n2][0], acc[(mh_)*4 + m2][(nh_)*2 + n2], 0, 0, 0);      \
        acc[(mh_)*4 + m2][(nh_)*2 + n2] = __builtin_amdgcn_mfma_f32_16x16x32_bf16( \
            A[m2][1], bfr_[n2][1], acc[(mh_)*4 + m2][(nh_)*2 + n2], 0, 0, 0);      \
      } }                                                                    \
    __builtin_amdgcn_s_setprio(0);                                           \
  } while (0)

// One K-tile. buf_ MUST be literal 0/1. SA_/SB_ compile-time guards;
// VM_ is the vmcnt statement at tile end (after MM_P3).
#define KTILE(buf_, g_, SA_, SB_, VM_) do {                                  \
    /* P0 */                                                                 \
    if (SA_) STAGE_A((buf_) ^ 1, (g_) + 1, 0);                               \
    BAR;                                                                     \
    RD_A(buf_, 0);                                                           \
    RD_B(buf_, 0, B0);                                                       \
    MM16(B0, 0, 0);                                                          \
    /* P1 */                                                                 \
    if (SA_) STAGE_A((buf_) ^ 1, (g_) + 1, 1);                               \
    BAR;                                                                     \
    RD_B(buf_, 1, B1);                                                       \
    MM16(B1, 0, 1);                                                          \
    /* P2 */                                                                 \
    if (SB_) STAGE_B(buf_, (g_) + 2, 0);                                     \
    BAR;                                                                     \
    RD_A(buf_, 1);                                                           \
    MM16(B0, 1, 0);                                                          \
    /* P3 */                                                                 \
    if (SB_) STAGE_B(buf_, (g_) + 2, 1);                                     \
    BAR;                                                                     \
    MM16(B1, 1, 1);                                                          \
    VM_;                                                                     \
  } while (0)

__global__ __launch_bounds__(512, 2) void gemm8_kernel(const unsigned short* __restrict__ xbf,
                                                       const unsigned short* __restrict__ weff,
                                                       const float* __restrict__ bias,
                                                       float* __restrict__ out) {
  __shared__ __attribute__((aligned(1024))) char lds[2][4][16384];  // 128 KiB

  const int tid  = threadIdx.x;
  const int lane = tid & 63;
  const int wid  = tid >> 6;
  const int wr   = wid >> 2;        // 0..1  (M half)
  const int wc   = wid & 3;         // 0..3  (N quarter)

  // bijective XCD swizzle: 1024 wgs, 8 XCDs -> each XCD gets 8 M-rows x 16 N-cols
  const int id  = blockIdx.x;
  const int nid = (id & 7) * 128 + (id >> 3);
  const int tn  = nid & 15;         // N tile (16)
  const int tm  = nid >> 4;         // M tile (64)

  // ds_read lane offsets (swizzled): addr = row*128 + ((kk*64 + (l>>4)*16) ^ ((l&7)<<4))
  const int rowb  = (lane & 15) * 128;
  const int kx    = (lane & 7) << 4;
  const int koff0 = (((lane >> 4) * 16) ^ kx);
  const int koff1 = ((64 + (lane >> 4) * 16) ^ kx);

  // staging lane offsets (inverse-swizzled source)
  const int sr = tid >> 3;                        // row within 64-row chunk
  const int ke = ((tid & 7) ^ (sr & 7)) * 8;      // permuted k-element offset
  const unsigned short* gA = xbf  + (size_t)(tm * BM + sr) * D_IN + ke;
  const unsigned short* gB = weff + (size_t)(tn * BN + sr) * D_IN + ke;

  f32x4 acc[8][4] = {};
  bf16x8 A[4][2], B0[2][2], B1[2][2];

  // prologue: tile 0 (A+B) -> buf0 ; B of tile 1 -> buf1  (12 loads)
  STAGE_A(0, 0, 0); STAGE_A(0, 0, 1);
  STAGE_B(0, 0, 0); STAGE_B(0, 0, 1);
  STAGE_B(1, 1, 0); STAGE_B(1, 1, 1);
  VMW(4);           // tile 0 fully landed; B(1)x4 stays in flight
                    // (tile 0's P0 barrier is the release point for all waves)

  for (int g = 0; g < KT - 2; g += 2) {
    KTILE(0, g,     1, 1, VMW(4));
    KTILE(1, g + 1, 1, 1, VMW(4));
  }
  // tile KT-2 (buf0): stages A(KT-1) only; end queue = B(KT-1)x4 + A(KT-1)x4
  //   -> full drain so tile KT-1 is complete before its P0 reads.
  KTILE(0, KT - 2, 1, 0, VMW(0));
  // tile KT-1 (buf1): pure compute
  KTILE(1, KT - 1, 0, 0, (void)0);

  // epilogue: C/D layout col = lane&15, row = (lane>>4)*4 + j  [m89-verified]
  const int row0 = tm * BM + wr * 128 + (lane >> 4) * 4;
  const int col0 = tn * BN + wc * 64 + (lane & 15);
#pragma unroll
  for (int n = 0; n < 4; ++n) {
    const int col = col0 + n * 16;
    const float bv = bias[col];
#pragma unroll
    for (int m = 0; m < 8; ++m) {
      const int r = row0 + m * 16;
#pragma unroll
      for (int j = 0; j < 4; ++j)
        out[(size_t)(r + j) * D_OUT + col] = acc[m][n][j] + bv;
    }
  }
}

extern "C" void kernel_launch(void* const* d_in, const int* in_sizes, int n_in,
                              void* d_out, int out_size, void* d_ws, size_t ws_size,
                              hipStream_t stream) {
  const float* x      = (const float*)d_in[0];
  const int*   codes  = (const int*)d_in[1];
  const float* scales = (const float*)d_in[2];
  const float* bias   = (const float*)d_in[3];
  const float* delta  = (const float*)d_in[4];
  float* out = (float*)d_out;

  unsigned short* xbf  = (unsigned short*)d_ws;                    // 128 MiB
  unsigned short* weff = xbf + (size_t)MTOT * D_IN;                // +32 MiB

  prep_x_kernel<<<(MTOT * D_IN) / (256 * 8), 256, 0, stream>>>(x, xbf);
  prep_w_kernel<<<(D_OUT * D_IN) / (256 * 8), 256, 0, stream>>>(codes, scales, delta, weff);

  gemm8_kernel<<<(MTOT / BM) * (D_OUT / BN), 512, 0, stream>>>(xbf, weff, bias, out);
}